// Round 12
// baseline (317.531 us; speedup 1.0000x reference)
//
#include <hip/hip_runtime.h>
#include <hip/hip_bf16.h>

// Sizes
constexpr int BATCH = 8192;
constexpr int NREAL = 2000;   // real feature / output-col count
constexpr int KSLOT = 2048;   // per-matrix padded K slot
constexpr int KPAD  = 6144;   // 3 * 2048
constexpr int NPAD  = 2048;   // padded N
constexpr int NT    = KPAD / 64;  // 96 K-tiles of 64

typedef short bf16x8 __attribute__((ext_vector_type(8)));
typedef float f32x4  __attribute__((ext_vector_type(4)));

__device__ inline void gload_lds16(const void* g, void* l) {
  __builtin_amdgcn_global_load_lds(
      (const __attribute__((address_space(1))) unsigned int*)g,
      (__attribute__((address_space(3))) unsigned int*)l,
      16, 0, 0);
}

__device__ inline unsigned short f2bf(float x) {
  union { float f; unsigned int u; } v;
  v.f = x;
  unsigned int r = v.u + 0x7fffu + ((v.u >> 16) & 1u);
  return (unsigned short)(r >> 16);
}

// ---------------------------------------------------------------------------
// Kernel 1: standardize (ddof=1) activations into A_cat [8192][6144] bf16.
// grid (8192, 3), block 256.
// ---------------------------------------------------------------------------
__global__ __launch_bounds__(256) void apack_kernel(
    const float* __restrict__ prev, const float* __restrict__ nxt,
    const float* __restrict__ selfa, unsigned short* __restrict__ Acat) {
  __shared__ float red[4];
  const int row = blockIdx.x;
  const int mat = blockIdx.y;
  const float* src = (mat == 0) ? prev : (mat == 1) ? nxt : selfa;
  const int t = threadIdx.x;

  float x[8];
  float s1 = 0.f;
  if (t < 250) {
    const float4* p = (const float4*)(src + (size_t)row * NREAL + t * 8);
    float4 a = p[0], b = p[1];
    x[0] = a.x; x[1] = a.y; x[2] = a.z; x[3] = a.w;
    x[4] = b.x; x[5] = b.y; x[6] = b.z; x[7] = b.w;
#pragma unroll
    for (int j = 0; j < 8; ++j) s1 += x[j];
  } else {
#pragma unroll
    for (int j = 0; j < 8; ++j) x[j] = 0.f;
  }
#pragma unroll
  for (int o = 32; o; o >>= 1) s1 += __shfl_xor(s1, o);
  if ((t & 63) == 0) red[t >> 6] = s1;
  __syncthreads();
  const float mean = (red[0] + red[1] + red[2] + red[3]) * (1.f / 2000.f);
  __syncthreads();

  float ss = 0.f;
  if (t < 250) {
#pragma unroll
    for (int j = 0; j < 8; ++j) { float d = x[j] - mean; ss += d * d; }
  }
#pragma unroll
  for (int o = 32; o; o >>= 1) ss += __shfl_xor(ss, o);
  if ((t & 63) == 0) red[t >> 6] = ss;
  __syncthreads();
  const float var = (red[0] + red[1] + red[2] + red[3]) * (1.f / 1999.f);
  const float scale = 1.f / (sqrtf(var) + 1e-8f);

  unsigned short o8[8];
  if (t < 250) {
#pragma unroll
    for (int j = 0; j < 8; ++j) o8[j] = f2bf((x[j] - mean) * scale);
  } else {
#pragma unroll
    for (int j = 0; j < 8; ++j) o8[j] = 0;
  }
  uint4 q;
  q.x = (unsigned)o8[0] | ((unsigned)o8[1] << 16);
  q.y = (unsigned)o8[2] | ((unsigned)o8[3] << 16);
  q.z = (unsigned)o8[4] | ((unsigned)o8[5] << 16);
  q.w = (unsigned)o8[6] | ((unsigned)o8[7] << 16);
  *(uint4*)(Acat + (size_t)row * KPAD + mat * KSLOT + t * 8) = q;
}

// ---------------------------------------------------------------------------
// Kernel 2: weight transpose-pack into fragment-ordered W_fr.
// W_fr slot (cb16, k32) = 1KB: lane l holds W[col=cb16*16+(l&15)]
// [k = k32*32 + (l>>4)*8 .. +8] as 8 bf16. k32 = mat*64 + klocal/32.
// grid (128, 3), block 256; LDS bounce for coalescing both sides.
// ---------------------------------------------------------------------------
__global__ __launch_bounds__(256) void wfrag_kernel(
    const float* __restrict__ fW, const float* __restrict__ bW,
    const float* __restrict__ lW, unsigned short* __restrict__ Wfr) {
  __shared__ unsigned short tile[16][520];
  const int cb16 = blockIdx.x;
  const int m = blockIdx.y;
  const float* src = (m == 0) ? fW : (m == 1) ? bW : lW;
  const int t = threadIdx.x;
  const int r = t >> 4;        // 0..15 row within col-block
  const int c = t & 15;        // 32-float chunk within 512-k stripe
  const int s = cb16 * 16 + r;
  const bool rowok = (s < NREAL);

  for (int kc0 = 0; kc0 < KSLOT; kc0 += 512) {
    // read phase: coalesced f32 reads along k, convert, LDS store
#pragma unroll
    for (int v = 0; v < 8; ++v) {
      const int k = kc0 + c * 32 + v * 4;
      float4 f = make_float4(0.f, 0.f, 0.f, 0.f);
      if (rowok && k < NREAL)
        f = *(const float4*)(src + (size_t)s * NREAL + k);
      tile[r][c * 32 + v * 4 + 0] = f2bf(f.x);
      tile[r][c * 32 + v * 4 + 1] = f2bf(f.y);
      tile[r][c * 32 + v * 4 + 2] = f2bf(f.z);
      tile[r][c * 32 + v * 4 + 3] = f2bf(f.w);
    }
    __syncthreads();
    // write phase: 16 slots of 1KB, fully coalesced
#pragma unroll
    for (int w = 0; w < 4; ++w) {
      const int slot = w * 4 + (t >> 6);     // 0..15
      const int lane = t & 63;
      const uint4 q = *(const uint4*)&tile[lane & 15][slot * 32 + (lane >> 4) * 8];
      *(uint4*)(Wfr + ((size_t)(cb16 * 192 + m * 64 + (kc0 >> 5) + slot) * 512)
                + lane * 8) = q;
    }
    __syncthreads();
  }
}

// ---------------------------------------------------------------------------
// Kernel 3: 256x256 bf16 GEMM, 16x16x32 MFMA, 8 waves (2M x 4N), 128x64/wave.
// B DIRECT-FROM-GLOBAL: fragment-packed W_fr -> 8 coalesced 1KB loads/tile
// into regs, prefetched 1 tile ahead (bcA/bcB ping-pong, static indices).
// A via LDS exactly as R9 (proven 0-conflict staging + XOR swizzle), dbuf
// 64 KB. LDS pipe/tile ~1790 cy < MFMA 2064 cy -> MFMA-heaviest for the
// first time. ONE vmcnt(0) + barrier per tile (all forced loads >=1 tile
// old). grid 256 (= 32 bm x 8 bn), block 512.
// ---------------------------------------------------------------------------
__global__ __launch_bounds__(512, 2) void gemm_kernel(
    const unsigned short* __restrict__ A,    // [8192][6144] bf16
    const unsigned short* __restrict__ Wfr,  // fragment-packed weights
    const float* __restrict__ fb, const float* __restrict__ bb,
    const float* __restrict__ lb,
    const float* __restrict__ selfact,       // [8192][2000] f32
    float* __restrict__ out) {               // [8192][2000] f32
  __shared__ unsigned short ldsA[2][2][8192];   // [buf][kq] 64 KiB
  unsigned short* ldsF = &ldsA[0][0][0];

  const int tid  = threadIdx.x;
  const int wave = tid >> 6;
  const int lane = tid & 63;
  const int wm = wave >> 2;     // 0..1
  const int wn = wave & 3;      // 0..3

  // XCD-aware block swizzle
  const int nbid = (blockIdx.x & 7) * 32 + (blockIdx.x >> 3);
  const int bm = nbid >> 3;     // 0..31
  const int bn = nbid & 7;      // 0..7

  // A staging source (R9 decode): srow=tid>>2, chunk=(tid&3)^((srow>>1)&3)
  const int srow = tid >> 2;
  const int sc = (tid & 3) ^ ((tid >> 3) & 3);
  const unsigned short* Asrc =
      A + (size_t)(bm * 256 + srow) * KPAD + sc * 8;

  // A fragment read base (R9): row = wm*128 + fm*16 + (lane&15)
  const int pcx = (lane >> 4) ^ ((lane >> 1) & 3);
  const unsigned short* aF = ldsF + (wm * 128 + (lane & 15)) * 32 + pcx * 8;

  // B fragment global base: cb16 = bn*16 + wn*4 + fn
  const unsigned short* Bbase =
      Wfr + (size_t)(bn * 16 + wn * 4) * 192 * 512 + lane * 8;

  f32x4 acc[8][4] = {};
  bf16x8 bcA[4][2], bcB[4][2];

#define STQ(bu, kq, rh, tt) { \
    const unsigned short* g_ = Asrc + (size_t)(rh) * 128 * KPAD + \
        (size_t)(tt) * 64 + (kq) * 32; \
    unsigned short* d_ = ldsF + ((bu) * 2 + (kq)) * 8192 + (rh) * 4096 + \
        wave * 512; \
    gload_lds16(g_, d_); \
  }
#define STAGE_A(bu, tt) { \
    STQ(bu, 0, 0, tt) STQ(bu, 0, 1, tt) STQ(bu, 1, 0, tt) STQ(bu, 1, 1, tt) }

#define LOADB(dst, tt) \
    _Pragma("unroll") for (int fn = 0; fn < 4; ++fn) \
    _Pragma("unroll") for (int kq = 0; kq < 2; ++kq) \
      dst[fn][kq] = *(const bf16x8*)(Bbase + (size_t)fn * 98304 + \
          ((size_t)(tt) * 2 + kq) * 512);

#define TILEB(q, tt, bcur, bnxt, DOB, DOST) { \
    if (DOB) { LOADB(bnxt, (tt) + 1) } \
    if (DOST) { STAGE_A((q) ^ 1, (tt) + 1) } \
    _Pragma("unroll") for (int kk = 0; kk < 2; ++kk) { \
      __builtin_amdgcn_s_setprio(1); \
      _Pragma("unroll") for (int fm = 0; fm < 8; ++fm) { \
        bf16x8 af = *(const bf16x8*)(aF + ((q) * 2 + kk) * 8192 + fm * 512); \
        _Pragma("unroll") for (int fn = 0; fn < 4; ++fn) \
          acc[fm][fn] = __builtin_amdgcn_mfma_f32_16x16x32_bf16( \
              af, bcur[fn][kk], acc[fm][fn], 0, 0, 0); \
      } \
      __builtin_amdgcn_s_setprio(0); \
    } \
    asm volatile("s_waitcnt vmcnt(0)" ::: "memory"); \
    __builtin_amdgcn_s_barrier(); \
    __builtin_amdgcn_sched_barrier(0); \
  }

  // Prologue: stage A(0), load B(0); publish.
  STAGE_A(0, 0)
  LOADB(bcA, 0)
  asm volatile("s_waitcnt vmcnt(0)" ::: "memory");
  __builtin_amdgcn_s_barrier();
  __builtin_amdgcn_sched_barrier(0);

  for (int i = 0; i < 47; ++i) {
    const int t = 2 * i;
    TILEB(0, t, bcA, bcB, true, true)
    TILEB(1, t + 1, bcB, bcA, true, true)
  }
  TILEB(0, 94, bcA, bcB, true, true)    // loads B(95), stages A(95)
  TILEB(1, 95, bcB, bcA, false, false)  // drain

  // Epilogue (R9-validated): col=lane&15, row=(lane>>4)*4+reg
  const int colLane = lane & 15;
  const int rowGrp  = (lane >> 4) * 4;
#pragma unroll
  for (int fn = 0; fn < 4; ++fn) {
    const int col = bn * 256 + wn * 64 + fn * 16 + colLane;
    if (col < NREAL) {
      const float bias = fb[col] + bb[col] + lb[col];
#pragma unroll
      for (int fm = 0; fm < 8; ++fm) {
        const int row0 = bm * 256 + wm * 128 + fm * 16 + rowGrp;
#pragma unroll
        for (int r = 0; r < 4; ++r) {
          const float pre = acc[fm][fn][r] + bias;
          const size_t oi = (size_t)(row0 + r) * NREAL + col;
          out[oi] = 0.7f * fmaxf(pre, 0.f) + 0.3f * selfact[oi];
        }
      }
    }
  }
#undef TILEB
#undef LOADB
#undef STAGE_A
#undef STQ
}

// ---------------------------------------------------------------------------
extern "C" void kernel_launch(void* const* d_in, const int* in_sizes, int n_in,
                              void* d_out, int out_size, void* d_ws,
                              size_t ws_size, hipStream_t stream) {
  const float* prev = (const float*)d_in[0];
  const float* selfa = (const float*)d_in[1];
  const float* nxt  = (const float*)d_in[2];
  const float* fW = (const float*)d_in[3];
  const float* fb = (const float*)d_in[4];
  const float* bW = (const float*)d_in[5];
  const float* bb = (const float*)d_in[6];
  const float* lW = (const float*)d_in[7];
  const float* lb = (const float*)d_in[8];
  float* out = (float*)d_out;

  unsigned short* Acat = (unsigned short*)d_ws;                 // 100.7 MB
  unsigned short* Wfr  = Acat + (size_t)BATCH * KPAD;           // +25.2 MB

  apack_kernel<<<dim3(BATCH, 3), 256, 0, stream>>>(prev, nxt, selfa, Acat);
  wfrag_kernel<<<dim3(128, 3), 256, 0, stream>>>(fW, bW, lW, Wfr);
  gemm_kernel<<<dim3(32 * 8), 512, 0, stream>>>(Acat, Wfr, fb, bb, lb,
                                                selfa, out);
}